// Round 8
// baseline (131.309 us; speedup 1.0000x reference)
//
#include <hip/hip_runtime.h>
#include <hip/hip_bf16.h>
#include <stdint.h>

// KipfMLPGNN: B=32, N=64 nodes, D=128, H=256, L=3 layers.
// Factorizations:
//  - First MLP layer split into per-node sender/receiver halves (k_T, fp16).
//  - Arc blend separates: agg = Sum_c (1-a)*m0 + Sum_c a*m1 -> phase = grid.z,
//    combined across blocks with f32 atomicAdd.
// k_edge v8: wave owns 32 d (4 waves = all 128 d, no dh split) -> h a-build
// duplication 8x -> 4x. Inner step: mt-pair x nt=2 = 4 independent MFMA
// chains interleaved (ILP covers MFMA latency). tr loads halved.
// ~215 VGPR @ 2 waves/SIMD (256 budget) - no spill.

#define NB 32
#define NN 64
#define DD 128
#define HH 256

typedef __attribute__((ext_vector_type(4))) float f32x4;
typedef __attribute__((ext_vector_type(8))) _Float16 f16x8;

__device__ __forceinline__ uint64_t cvt4h(f32x4 v) {
  union { _Float16 h[4]; uint64_t u; } x;
  x.h[0] = (_Float16)v[0]; x.h[1] = (_Float16)v[1];
  x.h[2] = (_Float16)v[2]; x.h[3] = (_Float16)v[3];
  return x.u;
}

// E[node][d] = table[x[node]][d]  (2048 x 128 f32)
__global__ __launch_bounds__(256) void k_gather(const int* __restrict__ x,
                                                const float* __restrict__ table,
                                                float* __restrict__ E) {
  int i = blockIdx.x * 256 + threadIdx.x;
  int node = i >> 5;
  ((f32x4*)E)[i] = ((const f32x4*)table)[(size_t)x[node] * 32 + (i & 31)];
}

// W1fp[2][256h][256in] fp16 (natural layout), W2fp[2][128d][256h] fp16.
__global__ __launch_bounds__(256) void k_prep(const float* __restrict__ W1_0,
                                              const float* __restrict__ W1_1,
                                              const float* __restrict__ W2_0,
                                              const float* __restrict__ W2_1,
                                              _Float16* __restrict__ W1fp,
                                              _Float16* __restrict__ W2fp) {
  int tid = blockIdx.x * 256 + threadIdx.x;   // 192*256 = 49152 f32x4 chunks
  const float* src; uint64_t* dst; int off;
  if (tid < 32768) {
    src = (tid < 16384) ? W1_0 : W1_1;
    off = tid & 16383;
    dst = (uint64_t*)W1fp + (tid >> 14) * 16384 + off;
  } else {
    int t2 = tid - 32768;
    src = (t2 < 8192) ? W2_0 : W2_1;
    off = t2 & 8191;
    dst = (uint64_t*)W2fp + (t2 >> 13) * 8192 + off;
  }
  *dst = cvt4h(((const f32x4*)src)[off]);
}

// Tfp[node][1024] = [Ts0 | Tr0+b1_0 | Ts1 | Tr1+b1_1]  (fp16)
// grid (8, 32): x = q*2+half (q in {Ts0,Tr0,Ts1,Tr1}, 128 h-cols), y = 64-node blk
__global__ __launch_bounds__(256) void k_T(const float* __restrict__ E,
                                           const _Float16* __restrict__ W1fp,
                                           const float* __restrict__ b1_0,
                                           const float* __restrict__ b1_1,
                                           _Float16* __restrict__ Tfp) {
  __shared__ char Els[64 * 256];     // 64 nodes x 128 f16, swizzled rows (256B)
  int t = threadIdx.x;
  int gi = blockIdx.x;
  int q = gi >> 1;                   // group 0..3
  int hb = (gi & 1) * 128;           // h-half
  int inoff = (q & 1) * 128;         // sender(0) / receiver(128) input half
  int node0 = blockIdx.y * 64;

  // stage E tile -> fp16 LDS, XOR swizzle ((row&7)<<4)
#pragma unroll
  for (int ii = 0; ii < 8; ++ii) {
    int idx = ii * 256 + t;          // f32x4 chunk: row=idx>>5, ck=idx&31
    int row = idx >> 5, ck = idx & 31;
    f32x4 v = ((const f32x4*)(E + (size_t)node0 * 128))[idx];
    *(uint64_t*)(Els + row * 256 + ((ck * 8) ^ ((row & 7) << 4))) = cvt4h(v);
  }
  __syncthreads();

  int lane = t & 63, w = t >> 6;     // 4 waves, each 64M x 32N
  int col = lane & 15, khi = lane >> 4;

  // hoist B fragments: W1fp[q>>1][hb+n][inoff + k]
  const _Float16* Wq = W1fp + (q >> 1) * 65536;
  f16x8 bfr[2][4];
#pragma unroll
  for (int nt = 0; nt < 2; ++nt) {
    int n = w * 32 + nt * 16 + col;
#pragma unroll
    for (int ks = 0; ks < 4; ++ks)
      bfr[nt][ks] = *(const f16x8*)(Wq + (hb + n) * 256 + inoff + ks * 32 + khi * 8);
  }

  f32x4 acc[4][2];
  const f32x4 z = {0.f, 0.f, 0.f, 0.f};
#pragma unroll
  for (int mt = 0; mt < 4; ++mt)
#pragma unroll
    for (int nt = 0; nt < 2; ++nt) acc[mt][nt] = z;

#pragma unroll
  for (int ks = 0; ks < 4; ++ks) {
    f16x8 a[4];
#pragma unroll
    for (int mt = 0; mt < 4; ++mt) {
      int c = mt * 16 + col;
      a[mt] = *(const f16x8*)(Els + c * 256 + ((ks * 64 + khi * 16) ^ ((c & 7) << 4)));
    }
#pragma unroll
    for (int mt = 0; mt < 4; ++mt)
#pragma unroll
      for (int nt = 0; nt < 2; ++nt)
        acc[mt][nt] = __builtin_amdgcn_mfma_f32_16x16x32_f16(a[mt], bfr[nt][ks],
                                                             acc[mt][nt], 0, 0, 0);
  }

  const float* b1q = (q >> 1) ? b1_1 : b1_0;
  float bv[2];
#pragma unroll
  for (int nt = 0; nt < 2; ++nt)
    bv[nt] = (q & 1) ? b1q[hb + w * 32 + nt * 16 + col] : 0.f;

#pragma unroll
  for (int mt = 0; mt < 4; ++mt)
#pragma unroll
    for (int nt = 0; nt < 2; ++nt)
#pragma unroll
      for (int j = 0; j < 4; ++j) {
        int node = node0 + mt * 16 + khi * 4 + j;
        int cgl = q * 256 + hb + w * 32 + nt * 16 + col;
        Tfp[(size_t)node * 1024 + cgl] = (_Float16)(acc[mt][nt][j] + bv[nt]);
      }
}

// out[b][d] = E[b][0][d]  (initializes d_out deterministically each call)
__global__ __launch_bounds__(256) void k_init(const float* __restrict__ E,
                                              float* __restrict__ out) {
  int i = blockIdx.x * 256 + threadIdx.x;      // 4096
  out[i] = E[(size_t)(i >> 7) * (NN * DD) + (i & 127)];
}

// k_edge v8: grid (nrb, 32, 2) — x: r-block(8 rows), y: batch, z: phase.
// Block 256 thr / 4 waves; wave w owns d-cols [w*32, w*32+32) (nt=2).
// Per wave: bv[2][8] (64 regs), per mt-pair ts0/ts1 (64), per-rr tr[8] (32),
// 4 interleaved MFMA chains per ks step. Epilogue: arc blend, c-sum shfl,
// atomicAdd into Eout.
template <int LAST>
__global__ __launch_bounds__(256) void k_edge(const _Float16* __restrict__ Tfp,
                                              const int* __restrict__ arcs,
                                              float* __restrict__ Eout,
                                              const _Float16* __restrict__ W2fp,
                                              const float* __restrict__ b2_0,
                                              const float* __restrict__ b2_1) {
  constexpr int NR = LAST ? 1 : 8;
  __shared__ char Tsl[64 * 512];     // 64 c-rows x 256 k fp16, XOR swizzled
  int t = threadIdx.x;
  int p = blockIdx.z, b = blockIdx.y;
  int rbase = blockIdx.x * 8;
  const _Float16* Tb = Tfp + (size_t)b * NN * 1024;

  // stage this phase's sender tile: 2048 x 16B chunks
#pragma unroll
  for (int it = 0; it < 8; ++it) {
    int idx = it * 256 + t, row = idx >> 5, ck = idx & 31;
    *(f16x8*)(Tsl + row * 512 + ((ck * 16) ^ ((row & 7) << 4))) =
        *(const f16x8*)(Tb + row * 1024 + p * 512 + ck * 8);
  }

  int lane = t & 63, w = t >> 6;
  int col = lane & 15, khi = lane >> 4;

  // hoist W2 column fragments for this wave's 32 d-cols (64 VGPR)
  const _Float16* W2p = W2fp + p * 32768;
  f16x8 bv[2][8];
#pragma unroll
  for (int nt = 0; nt < 2; ++nt) {
    int d = w * 32 + nt * 16 + col;
#pragma unroll
    for (int ks = 0; ks < 8; ++ks)
      bv[nt][ks] = *(const f16x8*)(W2p + d * 256 + ks * 32 + khi * 8);
  }
  const float* b2p = p ? b2_1 : b2_0;
  float b2v[2] = {b2p[w * 32 + col], b2p[w * 32 + 16 + col]};
  __syncthreads();

  float Sreg[NR][2];
#pragma unroll
  for (int rr = 0; rr < NR; ++rr) { Sreg[rr][0] = 0.f; Sreg[rr][1] = 0.f; }

#pragma unroll
  for (int pp = 0; pp < 2; ++pp) {
    int c0 = (pp * 2) * 16 + col;
    int c1 = (pp * 2 + 1) * 16 + col;
    f16x8 ts0[8], ts1[8];
#pragma unroll
    for (int ks = 0; ks < 8; ++ks) {
      ts0[ks] = *(const f16x8*)(Tsl + c0 * 512 +
                                ((ks * 64 + khi * 16) ^ ((c0 & 7) << 4)));
      ts1[ks] = *(const f16x8*)(Tsl + c1 * 512 +
                                ((ks * 64 + khi * 16) ^ ((c1 & 7) << 4)));
    }
#pragma unroll
    for (int rr = 0; rr < NR; ++rr) {
      int r = rbase + rr;
      const _Float16* trp = Tb + r * 1024 + p * 512 + 256 + khi * 8;
      f16x8 tr[8];
#pragma unroll
      for (int ks = 0; ks < 8; ++ks)
        tr[ks] = *(const f16x8*)(trp + ks * 32);

      f32x4 a00 = {0.f, 0.f, 0.f, 0.f}, a01 = a00, a10 = a00, a11 = a00;
#pragma unroll
      for (int ks = 0; ks < 8; ++ks) {
        f16x8 zv = {};
        f16x8 h0 = __builtin_elementwise_max(ts0[ks] + tr[ks], zv);
        f16x8 h1 = __builtin_elementwise_max(ts1[ks] + tr[ks], zv);
        a00 = __builtin_amdgcn_mfma_f32_16x16x32_f16(h0, bv[0][ks], a00, 0, 0, 0);
        a10 = __builtin_amdgcn_mfma_f32_16x16x32_f16(h1, bv[0][ks], a10, 0, 0, 0);
        a01 = __builtin_amdgcn_mfma_f32_16x16x32_f16(h0, bv[1][ks], a01, 0, 0, 0);
        a11 = __builtin_amdgcn_mfma_f32_16x16x32_f16(h1, bv[1][ks], a11, 0, 0, 0);
      }

      const int* arow = arcs + ((size_t)(b * NN + r)) * NN;
      const int4 ai0 = *(const int4*)(arow + (pp * 2) * 16 + khi * 4);
      const int4 ai1 = *(const int4*)(arow + (pp * 2 + 1) * 16 + khi * 4);
#pragma unroll
      for (int j = 0; j < 4; ++j) {
        int av0 = (j == 0) ? ai0.x : (j == 1) ? ai0.y : (j == 2) ? ai0.z : ai0.w;
        int av1 = (j == 0) ? ai1.x : (j == 1) ? ai1.y : (j == 2) ? ai1.z : ai1.w;
        float w0 = p ? (float)av0 : 1.0f - (float)av0;
        float w1 = p ? (float)av1 : 1.0f - (float)av1;
        Sreg[rr][0] = fmaf(w0, fmaxf(a00[j] + b2v[0], 0.f), Sreg[rr][0]);
        Sreg[rr][1] = fmaf(w0, fmaxf(a01[j] + b2v[1], 0.f), Sreg[rr][1]);
        Sreg[rr][0] = fmaf(w1, fmaxf(a10[j] + b2v[0], 0.f), Sreg[rr][0]);
        Sreg[rr][1] = fmaf(w1, fmaxf(a11[j] + b2v[1], 0.f), Sreg[rr][1]);
      }
    }
  }

#pragma unroll
  for (int rr = 0; rr < NR; ++rr) {
#pragma unroll
    for (int nt = 0; nt < 2; ++nt) {
      float v = Sreg[rr][nt];
      v += __shfl_xor(v, 16);
      v += __shfl_xor(v, 32);
      if (khi == 0) {
        int d = w * 32 + nt * 16 + col;
        if (LAST)
          atomicAdd(Eout + b * DD + d, v);
        else
          atomicAdd(Eout + ((size_t)(b * NN + rbase + rr)) * DD + d, v);
      }
    }
  }
}

extern "C" void kernel_launch(void* const* d_in, const int* in_sizes, int n_in,
                              void* d_out, int out_size, void* d_ws, size_t ws_size,
                              hipStream_t stream) {
  const int* x       = (const int*)d_in[0];
  const int* arcs    = (const int*)d_in[1];
  const float* table = (const float*)d_in[3];
  const float* W1_0  = (const float*)d_in[4];
  const float* b1_0  = (const float*)d_in[5];
  const float* W2_0  = (const float*)d_in[6];
  const float* b2_0  = (const float*)d_in[7];
  const float* W1_1  = (const float*)d_in[8];
  const float* b1_1  = (const float*)d_in[9];
  const float* W2_1  = (const float*)d_in[10];
  const float* b2_1  = (const float*)d_in[11];
  float* out = (float*)d_out;

  char* ws = (char*)d_ws;
  float* E         = (float*)ws;                      // 1 MB
  _Float16* Tfp    = (_Float16*)(ws + (1u << 20));    // 4 MB
  _Float16* W1fp   = (_Float16*)(ws + (5u << 20));    // 256 KB
  _Float16* W2fp   = (_Float16*)(ws + (5u << 20) + (256u << 10));  // 128 KB

  k_gather<<<256, 256, 0, stream>>>(x, table, E);
  k_prep<<<192, 256, 0, stream>>>(W1_0, W1_1, W2_0, W2_1, W1fp, W2fp);
  for (int l = 0; l < 3; ++l) {
    k_T<<<dim3(8, 32), 256, 0, stream>>>(E, W1fp, b1_0, b1_1, Tfp);
    if (l == 2) {
      k_init<<<16, 256, 0, stream>>>(E, out);
      k_edge<1><<<dim3(1, 32, 2), 256, 0, stream>>>(Tfp, arcs, out,
                                                    W2fp, b2_0, b2_1);
    } else {
      k_edge<0><<<dim3(8, 32, 2), 256, 0, stream>>>(Tfp, arcs, E,
                                                    W2fp, b2_0, b2_1);
    }
  }
}